// Round 3
// baseline (955.057 us; speedup 1.0000x reference)
//
#include <hip/hip_runtime.h>
#include <hip/hip_bf16.h>
#include <math.h>

// Problem constants
#define NN 50000
#define PP 200000
#define LL 6
#define DD 128      // IN_DIM == OUT_DIM
#define HH 4        // heads

// Tiling
#define TM 64       // paths per workgroup
#define NT 512      // threads per workgroup (8 waves)
#define HPAD 132    // fp32 row stride for final-h LDS (bank spread)

typedef __attribute__((ext_vector_type(8))) short short8;   // 8 bf16 (MFMA A/B frag)
typedef __attribute__((ext_vector_type(4))) float f32x4;    // MFMA C/D frag

__device__ __forceinline__ unsigned short f2bf(float v) {
    __hip_bfloat16 h = __float2bfloat16(v);
    return *(unsigned short*)&h;
}
__device__ __forceinline__ float fast_rcp(float x) { return __builtin_amdgcn_rcpf(x); }
__device__ __forceinline__ float fast_sigmoid(float x) {
    return fast_rcp(1.f + __expf(-x));            // v_exp + v_rcp, no div sequence
}
__device__ __forceinline__ float fast_tanh(float x) {
    // tanh(|x|) = (1-e)/(1+e), e = exp(-2|x|) in (0,1] -> no overflow; restore sign
    float e = __expf(-2.f * fabsf(x));
    float t = (1.f - e) * fast_rcp(1.f + e);
    return copysignf(t, x);
}

// ---------------------------------------------------------------------------
// Prep: cast x and weights to bf16. w_ih/w_hh [384][128] row-major is already
// MFMA B-fragment order (gate row, k-contiguous).
// ---------------------------------------------------------------------------
__global__ void prep_x_kernel(const float* __restrict__ x,
                              unsigned short* __restrict__ xb) {
    int i = blockIdx.x * 256 + threadIdx.x;
    if (i < NN * DD) xb[i] = f2bf(x[i]);
}
__global__ void prep_w_kernel(const float* __restrict__ w_ih,
                              const float* __restrict__ w_hh,
                              unsigned short* __restrict__ wib,
                              unsigned short* __restrict__ whb) {
    int i = blockIdx.x * 256 + threadIdx.x;
    if (i < 3 * DD * DD) { wib[i] = f2bf(w_ih[i]); whb[i] = f2bf(w_hh[i]); }
}

// ---------------------------------------------------------------------------
// Fused MFMA GRU + attention.
//  - wave w owns d-slice [16w,16w+16); gate triple {d,128+d,256+d} wave-local
//  - weights: 24 persistent B-frags in VGPRs (loaded once)
//  - x A-frags: direct global loads (L2-resident working set) — no LDS staging
//  - h: fp32 in registers (lane owns its 16 (p,d) cells across steps);
//       bf16 copy in XOR-swizzled double-buffered LDS for the cross-wave
//       h-phase A-frags; ONE barrier per step.
//  - swizzle: element (p,d) at p*128 + ((d>>3)^(p&15))*8 + (d&7)
//    -> A-frag read (8 consecutive d for row p) is one aligned b128 with
//       start banks forming a permutation (conflict-free minimum).
// ---------------------------------------------------------------------------
__global__ __launch_bounds__(NT, 2)
void gru_att_kernel(const unsigned short* __restrict__ xb,   // [N][128] bf16
                    const int*   __restrict__ path_list,
                    const unsigned short* __restrict__ wib,  // [384][128] bf16
                    const unsigned short* __restrict__ whb,  // [384][128] bf16
                    const float* __restrict__ b_ih,
                    const float* __restrict__ b_hh,
                    const float* __restrict__ a,             // [128][4]
                    float* __restrict__ att_sum,             // [N][4]
                    float* __restrict__ out)                 // [N][512]
{
    __shared__ __align__(16) unsigned short hsb[2][TM * DD]; // 2 x 16KB, swizzled
    __shared__ int   nodes_s[TM * LL];                       // 1.5KB
    __shared__ float hs_f[TM * HPAD];                        // 33KB (final h, fp32)
    __shared__ float attun[TM * HH];
    float* red_s = (float*)hsb[1];   // [TM][8][HH] = 8KB overlay, dead after loop

    const int tid  = threadIdx.x;
    const int lane = tid & 63;
    const int wave = tid >> 6;
    const int lcol = lane & 15;       // MFMA col (d) / A-row (path)
    const int quad = lane >> 4;       // 0..3
    const int d    = wave * 16 + lcol;
    const int p0   = blockIdx.x * TM;
    const int ko   = quad * 8;        // A/B frag k-offset within 32-chunk

    // ---- persistent B fragments (c=0:r, 1:z, 2:n) ----
    short8 Bx[3][4], Bh[3][4];
    #pragma unroll
    for (int c = 0; c < 3; ++c)
        #pragma unroll
        for (int ks = 0; ks < 4; ++ks) {
            Bx[c][ks] = *(const short8*)(wib + (size_t)(c * DD + d) * DD + ks * 32 + ko);
            Bh[c][ks] = *(const short8*)(whb + (size_t)(c * DD + d) * DD + ks * 32 + ko);
        }
    const float brz = b_ih[d]       + b_hh[d];
    const float bzz = b_ih[d + 128] + b_hh[d + 128];
    const float bin = b_ih[d + 256];
    const float bhn = b_hh[d + 256];

    // ---- stage path nodes; zero h buffer 0 ----
    for (int i = tid; i < TM * LL; i += NT) nodes_s[i] = path_list[(size_t)p0 * LL + i];
    for (int i = tid; i < TM * DD * 2 / 16; i += NT)
        ((uint4*)hsb[0])[i] = make_uint4(0u, 0u, 0u, 0u);

    float hreg[16];
    #pragma unroll
    for (int i = 0; i < 16; ++i) hreg[i] = 0.f;

    f32x4 accR[4], accZ[4], accN[4], accH[4];

    #pragma unroll
    for (int t = 0; t < LL; ++t) {
        __syncthreads();   // prev epilogue writes to buf[t&1] now visible
        const unsigned short* rbuf = hsb[t & 1];
        unsigned short*       wbuf = hsb[(t + 1) & 1];

        #pragma unroll
        for (int rt = 0; rt < 4; ++rt) {
            accR[rt] = (f32x4){brz, brz, brz, brz};
            accZ[rt] = (f32x4){bzz, bzz, bzz, bzz};
            accN[rt] = (f32x4){bin, bin, bin, bin};
            accH[rt] = (f32x4){bhn, bhn, bhn, bhn};
        }

        #pragma unroll
        for (int ks = 0; ks < 4; ++ks) {
            #pragma unroll
            for (int rt = 0; rt < 4; ++rt) {
                const int p = rt * 16 + lcol;
                int node = nodes_s[p * LL + t];
                short8 ax = *(const short8*)(xb + (size_t)node * DD + ks * 32 + ko);
                short8 ah = *(const short8*)(rbuf + p * DD + (((ks * 4 + quad) ^ lcol) * 8));
                accR[rt] = __builtin_amdgcn_mfma_f32_16x16x32_bf16(ax, Bx[0][ks], accR[rt], 0, 0, 0);
                accZ[rt] = __builtin_amdgcn_mfma_f32_16x16x32_bf16(ax, Bx[1][ks], accZ[rt], 0, 0, 0);
                accN[rt] = __builtin_amdgcn_mfma_f32_16x16x32_bf16(ax, Bx[2][ks], accN[rt], 0, 0, 0);
                accR[rt] = __builtin_amdgcn_mfma_f32_16x16x32_bf16(ah, Bh[0][ks], accR[rt], 0, 0, 0);
                accZ[rt] = __builtin_amdgcn_mfma_f32_16x16x32_bf16(ah, Bh[1][ks], accZ[rt], 0, 0, 0);
                accH[rt] = __builtin_amdgcn_mfma_f32_16x16x32_bf16(ah, Bh[2][ks], accH[rt], 0, 0, 0);
            }
        }

        // ---- GRU cell epilogue (wave-local, h in registers) ----
        // writes go to wbuf (!= rbuf), so no barrier needed before them
        #pragma unroll
        for (int rt = 0; rt < 4; ++rt) {
            #pragma unroll
            for (int r = 0; r < 4; ++r) {
                const int idx = rt * 4 + r;
                const int p   = rt * 16 + quad * 4 + r;   // C/D: row = quad*4 + reg
                float rg = fast_sigmoid(accR[rt][r]);
                float zg = fast_sigmoid(accZ[rt][r]);
                float ng = fast_tanh(accN[rt][r] + rg * accH[rt][r]);
                float hnew = fmaf(zg, hreg[idx] - ng, ng);
                hreg[idx] = hnew;
                if (t < LL - 1) {
                    wbuf[p * DD + (((d >> 3) ^ (p & 15)) * 8) + (d & 7)] = f2bf(hnew);
                } else {
                    hs_f[p * HPAD + d] = hnew;   // final step: fp32 for epilogue
                }
            }
        }
    }

    __syncthreads();   // hs_f complete; hsb dead -> red_s overlay safe

    // ---- attention logits: att_un[pi][h] = exp(lrelu(h_pi . a[:,h])) ----
    {
        int pi = tid >> 3, tt = tid & 7;
        float s0 = 0.f, s1 = 0.f, s2 = 0.f, s3 = 0.f;
        #pragma unroll
        for (int j = 0; j < 16; ++j) {
            int dd2 = tt * 16 + j;
            float hv = hs_f[pi * HPAD + dd2];
            float4 av = *(const float4*)(a + dd2 * 4);
            s0 += hv * av.x; s1 += hv * av.y; s2 += hv * av.z; s3 += hv * av.w;
        }
        float* rp = red_s + (pi * 8 + tt) * 4;
        rp[0] = s0; rp[1] = s1; rp[2] = s2; rp[3] = s3;
    }
    __syncthreads();
    if (tid < TM) {
        int pi = tid;
        int row = nodes_s[pi * LL + (LL - 1)];
        #pragma unroll
        for (int h = 0; h < HH; ++h) {
            float s = 0.f;
            #pragma unroll
            for (int tt = 0; tt < 8; ++tt) s += red_s[(pi * 8 + tt) * 4 + h];
            float lv = (s > 0.f) ? s : 0.2f * s;
            float e  = __expf(lv);
            attun[pi * HH + h] = e;
            atomicAdd(&att_sum[row * HH + h], e);
        }
    }
    __syncthreads();

    // ---- unnormalized numerator into out[row][h*128+d] ----
    for (int e = tid; e < TM * 512; e += NT) {
        int pi  = e >> 9;
        int c   = e & 511;
        int h   = c >> 7;
        int dd2 = c & 127;
        int row = nodes_s[pi * LL + (LL - 1)];
        float v = attun[pi * HH + h] * hs_f[pi * HPAD + dd2];
        atomicAdd(&out[(size_t)row * 512 + c], v);
    }
}

// ---------------------------------------------------------------------------
// Normalize: out[n][h*128+d] /= att_sum[n][h]  (guard empty nodes: 0/0 -> 0)
// ---------------------------------------------------------------------------
__global__ void normalize_kernel(float* __restrict__ out,
                                 const float* __restrict__ att_sum) {
    int i = blockIdx.x * 256 + threadIdx.x;
    if (i < NN * 512) {
        int n = i >> 9;
        int h = (i >> 7) & 3;
        float s = att_sum[n * HH + h];
        float v = out[i];
        out[i] = (s > 0.f) ? v / s : 0.f;
    }
}

extern "C" void kernel_launch(void* const* d_in, const int* in_sizes, int n_in,
                              void* d_out, int out_size, void* d_ws, size_t ws_size,
                              hipStream_t stream) {
    const float* x         = (const float*)d_in[0];
    const int*   path_list = (const int*)  d_in[1];
    const float* w_ih      = (const float*)d_in[2];
    const float* w_hh      = (const float*)d_in[3];
    const float* b_ih      = (const float*)d_in[4];
    const float* b_hh      = (const float*)d_in[5];
    const float* a         = (const float*)d_in[6];
    float* out = (float*)d_out;

    // workspace: att_sum | xb | wib | whb  (~13.8MB)
    float*          att_sum = (float*)d_ws;                       // 800000 B
    unsigned short* xb      = (unsigned short*)((char*)d_ws + 800000);
    unsigned short* wib     = xb + (size_t)NN * DD;
    unsigned short* whb     = wib + 3 * DD * DD;

    hipMemsetAsync(out, 0, (size_t)NN * 512 * sizeof(float), stream);
    hipMemsetAsync(att_sum, 0, (size_t)NN * HH * sizeof(float), stream);

    prep_x_kernel<<<(NN * DD + 255) / 256, 256, 0, stream>>>(x, xb);
    prep_w_kernel<<<(3 * DD * DD + 255) / 256, 256, 0, stream>>>(w_ih, w_hh, wib, whb);

    gru_att_kernel<<<PP / TM, NT, 0, stream>>>(xb, path_list, wib, whb,
                                               b_ih, b_hh, a, att_sum, out);

    normalize_kernel<<<(NN * 512 + 255) / 256, 256, 0, stream>>>(out, att_sum);
}

// Round 4
// 725.531 us; speedup vs baseline: 1.3164x; 1.3164x over previous
//
#include <hip/hip_runtime.h>
#include <hip/hip_bf16.h>
#include <math.h>

// Problem constants
#define NN 50000
#define PP 200000
#define LL 6
#define DD 128      // IN_DIM == OUT_DIM
#define HH 4        // heads

// Tiling
#define TM 64       // paths per workgroup
#define NT 512      // threads per workgroup (8 waves)
#define HPAD 132    // fp32 row stride for final-h LDS (bank spread)

typedef __attribute__((ext_vector_type(8))) short short8;   // 8 bf16 (MFMA A/B frag)
typedef __attribute__((ext_vector_type(4))) float f32x4;    // MFMA C/D frag

__device__ __forceinline__ unsigned short f2bf(float v) {
    __hip_bfloat16 h = __float2bfloat16(v);
    return *(unsigned short*)&h;
}
__device__ __forceinline__ float fast_rcp(float x) { return __builtin_amdgcn_rcpf(x); }
__device__ __forceinline__ float fast_sigmoid(float x) {
    return fast_rcp(1.f + __expf(-x));            // v_exp + v_rcp, no div sequence
}
__device__ __forceinline__ float fast_tanh(float x) {
    // tanh(|x|) = (1-e)/(1+e), e = exp(-2|x|) in (0,1] -> no overflow; restore sign
    float e = __expf(-2.f * fabsf(x));
    float t = (1.f - e) * fast_rcp(1.f + e);
    return copysignf(t, x);
}

// ---------------------------------------------------------------------------
// Prep: cast x and weights to bf16. w_ih/w_hh [384][128] row-major is already
// MFMA B-fragment order (gate row, k-contiguous).
// ---------------------------------------------------------------------------
__global__ void prep_x_kernel(const float* __restrict__ x,
                              unsigned short* __restrict__ xb) {
    int i = blockIdx.x * 256 + threadIdx.x;
    if (i < NN * DD) xb[i] = f2bf(x[i]);
}
__global__ void prep_w_kernel(const float* __restrict__ w_ih,
                              const float* __restrict__ w_hh,
                              unsigned short* __restrict__ wib,
                              unsigned short* __restrict__ whb) {
    int i = blockIdx.x * 256 + threadIdx.x;
    if (i < 3 * DD * DD) { wib[i] = f2bf(w_ih[i]); whb[i] = f2bf(w_hh[i]); }
}

// ---------------------------------------------------------------------------
// Fused MFMA GRU + attention (R4).
//  - wave w owns d-slice [16w,16w+16); gate triple {d,128+d,256+d} wave-local
//  - 24 persistent B-frags in VGPRs (loaded once per WG)
//  - h fp32 in registers; bf16 copy in XOR-swizzled single-buffer LDS
//  - x STAGED IN LDS (loaded once per WG per step, not once per wave):
//    prefetched into registers one step ahead, written to swizzled xs in the
//    next step's write phase -> global latency hidden behind MFMA+epilogue.
//  - swizzle: element (p,k) at p*128 + ((k>>3)^(p&15))*8 + (k&7)
//    -> all A-frag b128 reads hit every bank exactly 2x (free per m136).
//  - 2 barriers per step:
//      W: xg->xs, h->hsb writes | barrier1 | L: prefetch xg(t+1) |
//      M: MFMA reads            | barrier2 | E: epilogue (VALU)
// ---------------------------------------------------------------------------
__global__ __launch_bounds__(NT, 2)
void gru_att_kernel(const unsigned short* __restrict__ xb,   // [N][128] bf16
                    const int*   __restrict__ path_list,
                    const unsigned short* __restrict__ wib,  // [384][128] bf16
                    const unsigned short* __restrict__ whb,  // [384][128] bf16
                    const float* __restrict__ b_ih,
                    const float* __restrict__ b_hh,
                    const float* __restrict__ a,             // [128][4]
                    float* __restrict__ att_sum,             // [N][4]
                    float* __restrict__ out)                 // [N][512]
{
    __shared__ __align__(16) unsigned short hsb[TM * DD];    // 16KB swizzled h
    __shared__ __align__(16) unsigned short xs [TM * DD];    // 16KB swizzled x
    __shared__ int   nodes_s[TM * LL];                       // 1.5KB
    __shared__ float hs_f[TM * HPAD];                        // 33KB final h fp32
    __shared__ float attun[TM * HH];                         // 1KB
    float* red_s = (float*)xs;   // 8KB overlay, xs dead after t-loop

    const int tid  = threadIdx.x;
    const int lane = tid & 63;
    const int wave = tid >> 6;
    const int lcol = lane & 15;       // MFMA col (d) / A-row (path) index
    const int quad = lane >> 4;       // 0..3
    const int d    = wave * 16 + lcol;
    const int p0   = blockIdx.x * TM;
    const int ko   = quad * 8;        // B-frag k-offset within 32-chunk

    // ---- persistent B fragments (c=0:r, 1:z, 2:n) ----
    short8 Bx[3][4], Bh[3][4];
    #pragma unroll
    for (int c = 0; c < 3; ++c)
        #pragma unroll
        for (int ks = 0; ks < 4; ++ks) {
            Bx[c][ks] = *(const short8*)(wib + (size_t)(c * DD + d) * DD + ks * 32 + ko);
            Bh[c][ks] = *(const short8*)(whb + (size_t)(c * DD + d) * DD + ks * 32 + ko);
        }
    const float brz = b_ih[d]       + b_hh[d];
    const float bzz = b_ih[d + 128] + b_hh[d + 128];
    const float bin = b_ih[d + 256];
    const float bhn = b_hh[d + 256];

    // ---- stage path nodes; zero hsb ----
    for (int i = tid; i < TM * LL; i += NT) nodes_s[i] = path_list[(size_t)p0 * LL + i];
    for (int i = tid; i < TM * DD / 8; i += NT)
        ((uint4*)hsb)[i] = make_uint4(0u, 0u, 0u, 0u);

    float hreg[16];
    #pragma unroll
    for (int i = 0; i < 16; ++i) hreg[i] = 0.f;

    __syncthreads();   // nodes_s + hsb zero visible

    // ---- gather mapping for x staging: thread -> (path gpi, 32B chunk gtt)
    const int gpi = tid >> 3;
    const int gtt = tid & 7;
    const int gpm = gpi & 15;

    // prefetch x(0) into registers
    uint4 xg0, xg1;
    {
        int node = nodes_s[gpi * LL + 0];
        const uint4* src = (const uint4*)(xb + (size_t)node * DD + gtt * 16);
        xg0 = src[0]; xg1 = src[1];
    }

    f32x4 accR[4], accZ[4], accN[4], accH[4];

    #pragma unroll
    for (int t = 0; t < LL; ++t) {
        // ---- Phase W: write prefetched x(t) into swizzled xs ----
        {
            int kb0 = 2 * gtt, kb1 = 2 * gtt + 1;
            *(uint4*)(xs + gpi * DD + ((kb0 ^ gpm) * 8)) = xg0;
            *(uint4*)(xs + gpi * DD + ((kb1 ^ gpm) * 8)) = xg1;
        }
        __syncthreads();   // barrier1: xs(t) + hsb(t) visible to all waves

        // ---- Phase L: prefetch x(t+1) (in flight across MFMA + epilogue) ----
        if (t < LL - 1) {
            int node = nodes_s[gpi * LL + t + 1];
            const uint4* src = (const uint4*)(xb + (size_t)node * DD + gtt * 16);
            xg0 = src[0]; xg1 = src[1];
        }

        #pragma unroll
        for (int rt = 0; rt < 4; ++rt) {
            accR[rt] = (f32x4){brz, brz, brz, brz};
            accZ[rt] = (f32x4){bzz, bzz, bzz, bzz};
            accN[rt] = (f32x4){bin, bin, bin, bin};
            accH[rt] = (f32x4){bhn, bhn, bhn, bhn};
        }

        // ---- Phase M: MFMA (A-frags from swizzled LDS) ----
        #pragma unroll
        for (int ks = 0; ks < 4; ++ks) {
            const int kb = ks * 4 + quad;
            #pragma unroll
            for (int rt = 0; rt < 4; ++rt) {
                const int p = rt * 16 + lcol;
                short8 ax = *(const short8*)(xs  + p * DD + ((kb ^ lcol) * 8));
                short8 ah = *(const short8*)(hsb + p * DD + ((kb ^ lcol) * 8));
                accR[rt] = __builtin_amdgcn_mfma_f32_16x16x32_bf16(ax, Bx[0][ks], accR[rt], 0, 0, 0);
                accZ[rt] = __builtin_amdgcn_mfma_f32_16x16x32_bf16(ax, Bx[1][ks], accZ[rt], 0, 0, 0);
                accN[rt] = __builtin_amdgcn_mfma_f32_16x16x32_bf16(ax, Bx[2][ks], accN[rt], 0, 0, 0);
                accR[rt] = __builtin_amdgcn_mfma_f32_16x16x32_bf16(ah, Bh[0][ks], accR[rt], 0, 0, 0);
                accZ[rt] = __builtin_amdgcn_mfma_f32_16x16x32_bf16(ah, Bh[1][ks], accZ[rt], 0, 0, 0);
                accH[rt] = __builtin_amdgcn_mfma_f32_16x16x32_bf16(ah, Bh[2][ks], accH[rt], 0, 0, 0);
            }
        }
        __syncthreads();   // barrier2: all waves done reading xs/hsb

        // ---- Phase E: GRU cell epilogue (wave-local, h in registers) ----
        #pragma unroll
        for (int rt = 0; rt < 4; ++rt) {
            #pragma unroll
            for (int r = 0; r < 4; ++r) {
                const int idx = rt * 4 + r;
                const int p   = rt * 16 + quad * 4 + r;   // C/D: row = quad*4 + reg
                float rg = fast_sigmoid(accR[rt][r]);
                float zg = fast_sigmoid(accZ[rt][r]);
                float ng = fast_tanh(accN[rt][r] + rg * accH[rt][r]);
                float hnew = fmaf(zg, hreg[idx] - ng, ng);
                hreg[idx] = hnew;
                if (t < LL - 1) {
                    hsb[p * DD + (((d >> 3) ^ (p & 15)) * 8) + (d & 7)] = f2bf(hnew);
                } else {
                    hs_f[p * HPAD + d] = hnew;   // final step: fp32 for epilogue
                }
            }
        }
    }

    __syncthreads();   // hs_f complete; xs dead -> red_s overlay safe

    // ---- attention logits: att_un[pi][h] = exp(lrelu(h_pi . a[:,h])) ----
    {
        int pi = tid >> 3, tt = tid & 7;
        float s0 = 0.f, s1 = 0.f, s2 = 0.f, s3 = 0.f;
        #pragma unroll
        for (int j = 0; j < 16; ++j) {
            int dd2 = tt * 16 + j;
            float hv = hs_f[pi * HPAD + dd2];
            float4 av = *(const float4*)(a + dd2 * 4);
            s0 += hv * av.x; s1 += hv * av.y; s2 += hv * av.z; s3 += hv * av.w;
        }
        float* rp = red_s + (pi * 8 + tt) * 4;
        rp[0] = s0; rp[1] = s1; rp[2] = s2; rp[3] = s3;
    }
    __syncthreads();
    if (tid < TM) {
        int pi = tid;
        int row = nodes_s[pi * LL + (LL - 1)];
        #pragma unroll
        for (int h = 0; h < HH; ++h) {
            float s = 0.f;
            #pragma unroll
            for (int tt = 0; tt < 8; ++tt) s += red_s[(pi * 8 + tt) * 4 + h];
            float lv = (s > 0.f) ? s : 0.2f * s;
            float e  = __expf(lv);
            attun[pi * HH + h] = e;
            atomicAdd(&att_sum[row * HH + h], e);
        }
    }
    __syncthreads();

    // ---- unnormalized numerator into out[row][h*128+d] ----
    for (int e = tid; e < TM * 512; e += NT) {
        int pi  = e >> 9;
        int c   = e & 511;
        int h   = c >> 7;
        int dd2 = c & 127;
        int row = nodes_s[pi * LL + (LL - 1)];
        float v = attun[pi * HH + h] * hs_f[pi * HPAD + dd2];
        atomicAdd(&out[(size_t)row * 512 + c], v);
    }
}

// ---------------------------------------------------------------------------
// Normalize: out[n][h*128+d] /= att_sum[n][h]  (guard empty nodes: 0/0 -> 0)
// ---------------------------------------------------------------------------
__global__ void normalize_kernel(float* __restrict__ out,
                                 const float* __restrict__ att_sum) {
    int i = blockIdx.x * 256 + threadIdx.x;
    if (i < NN * 512) {
        int n = i >> 9;
        int h = (i >> 7) & 3;
        float s = att_sum[n * HH + h];
        float v = out[i];
        out[i] = (s > 0.f) ? v / s : 0.f;
    }
}

extern "C" void kernel_launch(void* const* d_in, const int* in_sizes, int n_in,
                              void* d_out, int out_size, void* d_ws, size_t ws_size,
                              hipStream_t stream) {
    const float* x         = (const float*)d_in[0];
    const int*   path_list = (const int*)  d_in[1];
    const float* w_ih      = (const float*)d_in[2];
    const float* w_hh      = (const float*)d_in[3];
    const float* b_ih      = (const float*)d_in[4];
    const float* b_hh      = (const float*)d_in[5];
    const float* a         = (const float*)d_in[6];
    float* out = (float*)d_out;

    // workspace: att_sum | xb | wib | whb  (~13.8MB)
    float*          att_sum = (float*)d_ws;                       // 800000 B
    unsigned short* xb      = (unsigned short*)((char*)d_ws + 800000);
    unsigned short* wib     = xb + (size_t)NN * DD;
    unsigned short* whb     = wib + 3 * DD * DD;

    hipMemsetAsync(out, 0, (size_t)NN * 512 * sizeof(float), stream);
    hipMemsetAsync(att_sum, 0, (size_t)NN * HH * sizeof(float), stream);

    prep_x_kernel<<<(NN * DD + 255) / 256, 256, 0, stream>>>(x, xb);
    prep_w_kernel<<<(3 * DD * DD + 255) / 256, 256, 0, stream>>>(w_ih, w_hh, wib, whb);

    gru_att_kernel<<<PP / TM, NT, 0, stream>>>(xb, path_list, wib, whb,
                                               b_ih, b_hh, a, att_sum, out);

    normalize_kernel<<<(NN * 512 + 255) / 256, 256, 0, stream>>>(out, att_sum);
}

// Round 5
// 654.948 us; speedup vs baseline: 1.4582x; 1.1078x over previous
//
#include <hip/hip_runtime.h>
#include <hip/hip_bf16.h>
#include <math.h>

// Problem constants
#define NN 50000
#define PP 200000
#define LL 6
#define DD 128      // IN_DIM == OUT_DIM
#define HH 4        // heads

// Tiling
#define TM 64       // paths per workgroup
#define NT 512      // threads per workgroup (8 waves)
#define HPAD 132    // fp32 row stride for final-h LDS (bank spread)

typedef __attribute__((ext_vector_type(8))) short short8;   // 8 bf16 (MFMA A/B frag)
typedef __attribute__((ext_vector_type(4))) float f32x4;    // MFMA C/D frag

__device__ __forceinline__ unsigned short f2bf(float v) {
    __hip_bfloat16 h = __float2bfloat16(v);
    return *(unsigned short*)&h;
}
__device__ __forceinline__ float bf2f(unsigned short u) {
    union { unsigned int i; float f; } c; c.i = ((unsigned int)u) << 16; return c.f;
}
__device__ __forceinline__ float fast_rcp(float x) { return __builtin_amdgcn_rcpf(x); }
__device__ __forceinline__ float fast_sigmoid(float x) {
    return fast_rcp(1.f + __expf(-x));
}
__device__ __forceinline__ float fast_tanh(float x) {
    float e = __expf(-2.f * fabsf(x));
    float t = (1.f - e) * fast_rcp(1.f + e);
    return copysignf(t, x);
}

// ---------------------------------------------------------------------------
// Prep: cast x and weights to bf16.
// ---------------------------------------------------------------------------
__global__ void prep_x_kernel(const float* __restrict__ x,
                              unsigned short* __restrict__ xb) {
    int i = blockIdx.x * 256 + threadIdx.x;
    if (i < NN * DD) xb[i] = f2bf(x[i]);
}
__global__ void prep_w_kernel(const float* __restrict__ w_ih,
                              const float* __restrict__ w_hh,
                              unsigned short* __restrict__ wib,
                              unsigned short* __restrict__ whb) {
    int i = blockIdx.x * 256 + threadIdx.x;
    if (i < 3 * DD * DD) { wib[i] = f2bf(w_ih[i]); whb[i] = f2bf(w_hh[i]); }
}

// ---------------------------------------------------------------------------
// Counting sort of paths by destination row (= path_list[p][5]).
// ---------------------------------------------------------------------------
__global__ void histo_kernel(const int* __restrict__ path_list,
                             int* __restrict__ cnt) {
    int p = blockIdx.x * 256 + threadIdx.x;
    if (p < PP) atomicAdd(&cnt[path_list[p * LL + (LL - 1)]], 1);
}

// One-WG scan. Thread t owns strided indices {t, t+256, ...}; ordering of
// segments is thread-major — any disjoint covering is valid for pass B.
__global__ void scan_kernel(const int* __restrict__ cnt,
                            int* __restrict__ offs,
                            int* __restrict__ cursor) {
    __shared__ int ls[256];
    const int t = threadIdx.x;
    const int chunk = (NN + 255) / 256;
    int s = 0;
    for (int j = 0; j < chunk; ++j) {
        int i = t + j * 256;
        if (i < NN) s += cnt[i];
    }
    ls[t] = s; __syncthreads();
    for (int off = 1; off < 256; off <<= 1) {
        int v = (t >= off) ? ls[t - off] : 0;
        __syncthreads();
        ls[t] += v;
        __syncthreads();
    }
    int run = (t == 0) ? 0 : ls[t - 1];
    for (int j = 0; j < chunk; ++j) {
        int i = t + j * 256;
        if (i < NN) { offs[i] = run; cursor[i] = run; run += cnt[i]; }
    }
}

__global__ void scatter_kernel(const int* __restrict__ path_list,
                               int* __restrict__ cursor,
                               int* __restrict__ sorted) {
    int p = blockIdx.x * 256 + threadIdx.x;
    if (p < PP) {
        int row = path_list[p * LL + (LL - 1)];
        int k = atomicAdd(&cursor[row], 1);
        sorted[k] = p;
    }
}

// ---------------------------------------------------------------------------
// Pass A: fused MFMA GRU. Emits per-path embedding (bf16) + att_un (fp32)
// + atomic att_sum. NO output scatter (that's pass B, atomic-free).
//  - wave w owns d-slice [16w,16w+16); gate triple wave-local
//  - 24 persistent B-frags in VGPRs; h fp32 in registers
//  - x prefetched one step ahead, staged via XOR-swizzled LDS
//  - hs_f (final h, fp32) ALIASES the dead hsb+xs region -> LDS 44.5 KB
// ---------------------------------------------------------------------------
__global__ __launch_bounds__(NT, 2)
void gru_att_kernel(const unsigned short* __restrict__ xb,   // [N][128] bf16
                    const int*   __restrict__ path_list,
                    const unsigned short* __restrict__ wib,  // [384][128] bf16
                    const unsigned short* __restrict__ whb,  // [384][128] bf16
                    const float* __restrict__ b_ih,
                    const float* __restrict__ b_hh,
                    const float* __restrict__ a,             // [128][4]
                    float* __restrict__ att_sum,             // [N][4]
                    unsigned short* __restrict__ emb,        // [P][128] bf16
                    float* __restrict__ att_un_g)            // [P][4]
{
    // smem: [0,16384) hsb | [16384,32768) xs | hs_f fp32 aliases [0,33792)
    //       [33792,41984) red_s | [41984,43520) nodes_s
    __shared__ __align__(16) unsigned char smem[43520];
    unsigned short* hsb    = (unsigned short*)smem;
    unsigned short* xs     = (unsigned short*)(smem + 16384);
    float*          hs_f   = (float*)smem;                 // alias (final step only)
    float*          red_s  = (float*)(smem + 33792);       // [64][8][4]
    int*            nodes_s= (int*)(smem + 41984);         // [TM*LL]

    const int tid  = threadIdx.x;
    const int lane = tid & 63;
    const int wave = tid >> 6;
    const int lcol = lane & 15;
    const int quad = lane >> 4;
    const int d    = wave * 16 + lcol;
    const int p0   = blockIdx.x * TM;
    const int ko   = quad * 8;

    // persistent B fragments (c=0:r, 1:z, 2:n)
    short8 Bx[3][4], Bh[3][4];
    #pragma unroll
    for (int c = 0; c < 3; ++c)
        #pragma unroll
        for (int ks = 0; ks < 4; ++ks) {
            Bx[c][ks] = *(const short8*)(wib + (size_t)(c * DD + d) * DD + ks * 32 + ko);
            Bh[c][ks] = *(const short8*)(whb + (size_t)(c * DD + d) * DD + ks * 32 + ko);
        }
    const float brz = b_ih[d]       + b_hh[d];
    const float bzz = b_ih[d + 128] + b_hh[d + 128];
    const float bin = b_ih[d + 256];
    const float bhn = b_hh[d + 256];

    for (int i = tid; i < TM * LL; i += NT) nodes_s[i] = path_list[(size_t)p0 * LL + i];
    for (int i = tid; i < TM * DD / 8; i += NT)
        ((uint4*)hsb)[i] = make_uint4(0u, 0u, 0u, 0u);

    float hreg[16];
    #pragma unroll
    for (int i = 0; i < 16; ++i) hreg[i] = 0.f;

    __syncthreads();   // nodes_s + hsb zero visible

    const int gpi = tid >> 3;
    const int gtt = tid & 7;
    const int gpm = gpi & 15;

    uint4 xg0, xg1;
    {
        int node = nodes_s[gpi * LL + 0];
        const uint4* src = (const uint4*)(xb + (size_t)node * DD + gtt * 16);
        xg0 = src[0]; xg1 = src[1];
    }

    f32x4 accR[4], accZ[4], accN[4], accH[4];

    #pragma unroll
    for (int t = 0; t < LL; ++t) {
        // Phase W: write prefetched x(t) into swizzled xs
        {
            int kb0 = 2 * gtt, kb1 = 2 * gtt + 1;
            *(uint4*)(xs + gpi * DD + ((kb0 ^ gpm) * 8)) = xg0;
            *(uint4*)(xs + gpi * DD + ((kb1 ^ gpm) * 8)) = xg1;
        }
        __syncthreads();   // barrier1

        // Phase L: prefetch x(t+1)
        if (t < LL - 1) {
            int node = nodes_s[gpi * LL + t + 1];
            const uint4* src = (const uint4*)(xb + (size_t)node * DD + gtt * 16);
            xg0 = src[0]; xg1 = src[1];
        }

        #pragma unroll
        for (int rt = 0; rt < 4; ++rt) {
            accR[rt] = (f32x4){brz, brz, brz, brz};
            accZ[rt] = (f32x4){bzz, bzz, bzz, bzz};
            accN[rt] = (f32x4){bin, bin, bin, bin};
            accH[rt] = (f32x4){bhn, bhn, bhn, bhn};
        }

        // Phase M: MFMA
        #pragma unroll
        for (int ks = 0; ks < 4; ++ks) {
            const int kb = ks * 4 + quad;
            #pragma unroll
            for (int rt = 0; rt < 4; ++rt) {
                const int p = rt * 16 + lcol;
                short8 ax = *(const short8*)(xs  + p * DD + ((kb ^ lcol) * 8));
                short8 ah = *(const short8*)(hsb + p * DD + ((kb ^ lcol) * 8));
                accR[rt] = __builtin_amdgcn_mfma_f32_16x16x32_bf16(ax, Bx[0][ks], accR[rt], 0, 0, 0);
                accZ[rt] = __builtin_amdgcn_mfma_f32_16x16x32_bf16(ax, Bx[1][ks], accZ[rt], 0, 0, 0);
                accN[rt] = __builtin_amdgcn_mfma_f32_16x16x32_bf16(ax, Bx[2][ks], accN[rt], 0, 0, 0);
                accR[rt] = __builtin_amdgcn_mfma_f32_16x16x32_bf16(ah, Bh[0][ks], accR[rt], 0, 0, 0);
                accZ[rt] = __builtin_amdgcn_mfma_f32_16x16x32_bf16(ah, Bh[1][ks], accZ[rt], 0, 0, 0);
                accH[rt] = __builtin_amdgcn_mfma_f32_16x16x32_bf16(ah, Bh[2][ks], accH[rt], 0, 0, 0);
            }
        }
        __syncthreads();   // barrier2: xs/hsb reads done (alias-safe for hs_f)

        // Phase E: GRU cell epilogue
        #pragma unroll
        for (int rt = 0; rt < 4; ++rt) {
            #pragma unroll
            for (int r = 0; r < 4; ++r) {
                const int idx = rt * 4 + r;
                const int p   = rt * 16 + quad * 4 + r;
                float rg = fast_sigmoid(accR[rt][r]);
                float zg = fast_sigmoid(accZ[rt][r]);
                float ng = fast_tanh(accN[rt][r] + rg * accH[rt][r]);
                float hnew = fmaf(zg, hreg[idx] - ng, ng);
                hreg[idx] = hnew;
                if (t < LL - 1) {
                    hsb[p * DD + (((d >> 3) ^ (p & 15)) * 8) + (d & 7)] = f2bf(hnew);
                } else {
                    hs_f[p * HPAD + d] = hnew;   // fp32, aliases dead hsb/xs
                }
            }
        }
    }

    __syncthreads();   // hs_f complete

    // attention logits + emit bf16 path embedding
    {
        int pi = tid >> 3, tt = tid & 7;
        float s0 = 0.f, s1 = 0.f, s2 = 0.f, s3 = 0.f;
        unsigned short pack[16];
        #pragma unroll
        for (int j = 0; j < 16; ++j) {
            int dd2 = tt * 16 + j;
            float hv = hs_f[pi * HPAD + dd2];
            pack[j] = f2bf(hv);
            float4 av = *(const float4*)(a + dd2 * 4);
            s0 += hv * av.x; s1 += hv * av.y; s2 += hv * av.z; s3 += hv * av.w;
        }
        uint4* dst = (uint4*)(emb + (size_t)(p0 + pi) * DD + tt * 16);
        dst[0] = *(uint4*)&pack[0];
        dst[1] = *(uint4*)&pack[8];
        float* rp = red_s + (pi * 8 + tt) * 4;
        rp[0] = s0; rp[1] = s1; rp[2] = s2; rp[3] = s3;
    }
    __syncthreads();
    if (tid < TM) {
        int pi = tid;
        int row = nodes_s[pi * LL + (LL - 1)];
        float4 e4;
        #pragma unroll
        for (int h = 0; h < HH; ++h) {
            float s = 0.f;
            #pragma unroll
            for (int tt = 0; tt < 8; ++tt) s += red_s[(pi * 8 + tt) * 4 + h];
            float lv = (s > 0.f) ? s : 0.2f * s;
            float e  = __expf(lv);
            ((float*)&e4)[h] = e;
            atomicAdd(&att_sum[row * HH + h], e);
        }
        *(float4*)(att_un_g + (size_t)(p0 + pi) * HH) = e4;
    }
}

// ---------------------------------------------------------------------------
// Pass B: per-node aggregation over its sorted paths. Atomic-free; writes
// every output element exactly once (empty nodes -> 0).
// 2 nodes per 256-thread WG; thread d in [0,128) owns column d of all heads.
// ---------------------------------------------------------------------------
__global__ __launch_bounds__(256)
void agg_kernel(const unsigned short* __restrict__ emb,   // [P][128] bf16
                const float* __restrict__ att_un,         // [P][4]
                const float* __restrict__ att_sum,        // [N][4]
                const int* __restrict__ offs,
                const int* __restrict__ cnt,
                const int* __restrict__ sorted,
                float* __restrict__ out)                  // [N][512]
{
    int node = blockIdx.x * 2 + (threadIdx.x >> 7);
    int d    = threadIdx.x & 127;
    if (node >= NN) return;
    int start = offs[node];
    int len   = cnt[node];
    float a0 = 0.f, a1 = 0.f, a2 = 0.f, a3 = 0.f;
    for (int i = 0; i < len; ++i) {
        int p = sorted[start + i];
        float4 at = *(const float4*)(att_un + (size_t)p * 4);
        float ev = bf2f(emb[(size_t)p * DD + d]);
        a0 = fmaf(at.x, ev, a0);
        a1 = fmaf(at.y, ev, a1);
        a2 = fmaf(at.z, ev, a2);
        a3 = fmaf(at.w, ev, a3);
    }
    float4 s = *(const float4*)(att_sum + (size_t)node * 4);
    float* o = out + (size_t)node * 512 + d;
    o[0]   = (s.x > 0.f) ? a0 / s.x : 0.f;
    o[128] = (s.y > 0.f) ? a1 / s.y : 0.f;
    o[256] = (s.z > 0.f) ? a2 / s.z : 0.f;
    o[384] = (s.w > 0.f) ? a3 / s.w : 0.f;
}

extern "C" void kernel_launch(void* const* d_in, const int* in_sizes, int n_in,
                              void* d_out, int out_size, void* d_ws, size_t ws_size,
                              hipStream_t stream) {
    const float* x         = (const float*)d_in[0];
    const int*   path_list = (const int*)  d_in[1];
    const float* w_ih      = (const float*)d_in[2];
    const float* w_hh      = (const float*)d_in[3];
    const float* b_ih      = (const float*)d_in[4];
    const float* b_hh      = (const float*)d_in[5];
    const float* a         = (const float*)d_in[6];
    float* out = (float*)d_out;

    // workspace layout (all 16B-multiple sizes), total ~69.5 MB
    char* w = (char*)d_ws;
    float*          att_sum = (float*)w;                 w += 800000;       // N*4 f32
    int*            cnt     = (int*)w;                   w += 200000;       // N
    int*            offs    = (int*)w;                   w += 200000;       // N
    int*            cursor  = (int*)w;                   w += 200000;       // N
    int*            sorted  = (int*)w;                   w += 800000;       // P
    float*          att_un  = (float*)w;                 w += 3200000;      // P*4 f32
    unsigned short* xb      = (unsigned short*)w;        w += 12800000;     // N*128 bf16
    unsigned short* wib     = (unsigned short*)w;        w += 98304;        // 384*128 bf16
    unsigned short* whb     = (unsigned short*)w;        w += 98304;
    unsigned short* emb     = (unsigned short*)w;        w += 51200000;     // P*128 bf16

    hipMemsetAsync(att_sum, 0, 800000, stream);
    hipMemsetAsync(cnt, 0, 200000, stream);

    prep_x_kernel<<<(NN * DD + 255) / 256, 256, 0, stream>>>(x, xb);
    prep_w_kernel<<<(3 * DD * DD + 255) / 256, 256, 0, stream>>>(w_ih, w_hh, wib, whb);

    histo_kernel<<<(PP + 255) / 256, 256, 0, stream>>>(path_list, cnt);
    scan_kernel<<<1, 256, 0, stream>>>(cnt, offs, cursor);
    scatter_kernel<<<(PP + 255) / 256, 256, 0, stream>>>(path_list, cursor, sorted);

    gru_att_kernel<<<PP / TM, NT, 0, stream>>>(xb, path_list, wib, whb,
                                               b_ih, b_hh, a, att_sum, emb, att_un);

    agg_kernel<<<(NN + 1) / 2, 256, 0, stream>>>(emb, att_un, att_sum,
                                                 offs, cnt, sorted, out);
}